// Round 8
// baseline (27.211 us; speedup 1.0000x reference)
//
#include <hip/hip_runtime.h>
#include <math.h>

#define FFT_N   4096
#define THREADS 256
#define RH 0.70710678118654752f
#define C16 0.92387953251128676f     // cos(2*pi/16)
#define S16 0.38268343236508977f     // sin(2*pi/16)
#define NEG2PI_256  (-2.45436926061702597e-2f)   // -2*pi/256
#define NEG2PI_4096 (-1.53398078788564123e-3f)   // -2*pi/4096

// Output-position map of dft16: X[k] lives in v[POS(k)].
#define POS(k) ((((k) & 3) << 2) | ((k) >> 2))

__device__ __forceinline__ float2 cmul(float2 a, float2 b) {
    return make_float2(a.x * b.x - a.y * b.y, a.x * b.y + a.y * b.x);
}

// Barrier WITHOUT vmcnt drain: LDS correctness only needs lgkmcnt(0).
__device__ __forceinline__ void bar_lds() {
    asm volatile("s_waitcnt lgkmcnt(0)" ::: "memory");
    __builtin_amdgcn_s_barrier();
}

// In-place DFT-4 (W4 = -i): natural in, natural out.
__device__ __forceinline__ void dft4(float2& a, float2& b, float2& c, float2& d) {
    float2 t0 = make_float2(a.x + c.x, a.y + c.y);
    float2 t1 = make_float2(a.x - c.x, a.y - c.y);
    float2 t2 = make_float2(b.x + d.x, b.y + d.y);
    float2 t3 = make_float2(b.y - d.y, d.x - b.x);   // -i * (b - d)
    a = make_float2(t0.x + t2.x, t0.y + t2.y);
    b = make_float2(t1.x + t3.x, t1.y + t3.y);
    c = make_float2(t0.x - t2.x, t0.y - t2.y);
    d = make_float2(t1.x - t3.x, t1.y - t3.y);
}

// Multiply by W16^E = exp(-2*pi*i*E/16); constant-folded forms.
template<int E>
__device__ __forceinline__ float2 mw16(float2 z) {
    if constexpr (E == 0) return z;
    else if constexpr (E == 4) return make_float2(z.y, -z.x);                    // -i
    else if constexpr (E == 2) return make_float2(RH * (z.x + z.y), RH * (z.y - z.x));
    else if constexpr (E == 6) return make_float2(RH * (z.y - z.x), -RH * (z.x + z.y));
    else if constexpr (E == 1) return cmul(z, make_float2(C16, -S16));
    else if constexpr (E == 3) return cmul(z, make_float2(S16, -C16));
    else /* E == 9 */          return cmul(z, make_float2(-C16, S16));
}

// 16-point DFT, natural input order; output X[k] at v[POS(k)].
__device__ __forceinline__ void dft16(float2 (&v)[16]) {
    dft4(v[0], v[4], v[8],  v[12]);
    dft4(v[1], v[5], v[9],  v[13]);
    dft4(v[2], v[6], v[10], v[14]);
    dft4(v[3], v[7], v[11], v[15]);
    v[5]  = mw16<1>(v[5]);   v[9]  = mw16<2>(v[9]);   v[13] = mw16<3>(v[13]);
    v[6]  = mw16<2>(v[6]);   v[10] = mw16<4>(v[10]);  v[14] = mw16<6>(v[14]);
    v[7]  = mw16<3>(v[7]);   v[11] = mw16<6>(v[11]);  v[15] = mw16<9>(v[15]);
    dft4(v[0],  v[1],  v[2],  v[3]);
    dft4(v[4],  v[5],  v[6],  v[7]);
    dft4(v[8],  v[9],  v[10], v[11]);
    dft4(v[12], v[13], v[14], v[15]);
}

// 4096 = 16*16*16 DIT: n = n1 + 16*n2 + 256*n3, k = k3 + 16*k2 + 256*k1.
// Half-size LDS (16 KB): both transposes done in two 8-slice chunks.
// RT1 layout: addr = n1 + 16*k3 + 256*(n2&7)   (chunk = n2>>3; writer n2 = hi)
// RT2 layout: addr = (n1^k3) + 16*k3 + 256*(k2&7) (chunk = k2>>3; reader k2 = hi)
__global__ __launch_bounds__(THREADS)
void fft4096_r16c(const float* __restrict__ xre, const float* __restrict__ xim,
                  float* __restrict__ yre, float* __restrict__ yim)
{
    __shared__ float2 sd[FFT_N / 2];   // 16 KB -> 8 blocks/CU (wave-capped)

    const int t  = threadIdx.x;
    const int lo = t & 15;             // A: n1 ; B: n1 ; C: k3
    const int hi = t >> 4;             // A: n2 ; B: k3 ; C: k2
    const bool lowhalf = (hi < 8);     // wave-uniform (waves 0,1)
    const size_t off = (size_t)blockIdx.x * FFT_N;
    const float* xr = xre + off;
    const float* xi = xim + off;

    // ---- Stage A: coalesced stride-256 gather, DFT16 over n3 ----
    float2 v[16];
    #pragma unroll
    for (int n3 = 0; n3 < 16; ++n3) {
        v[n3].x = xr[t + (n3 << 8)];
        v[n3].y = xi[t + (n3 << 8)];
    }
    dft16(v);

    // Twiddle W256^{n2*k3} = b[k3&3]*c[k3>>2]  (n2 = hi)
    float2 b[4], c[4];
    {
        float sn, cs;
        __sincosf((float)hi * NEG2PI_256, &sn, &cs);
        b[0] = make_float2(1.f, 0.f);
        b[1] = make_float2(cs, sn);
        b[2] = cmul(b[1], b[1]);
        b[3] = cmul(b[2], b[1]);
        c[0] = make_float2(1.f, 0.f);
        c[1] = cmul(b[2], b[2]);        // W256^{4*hi}
        c[2] = cmul(c[1], c[1]);
        c[3] = cmul(c[2], c[1]);
    }

    // ---- RT1, chunk 0 (n2 < 8): low waves write their n2-slice ----
    if (lowhalf) {
        #pragma unroll
        for (int k3 = 0; k3 < 16; ++k3) {
            float2 z = v[POS(k3)];
            if (k3 & 3)  z = cmul(z, b[k3 & 3]);
            if (k3 >> 2) z = cmul(z, c[k3 >> 2]);
            sd[lo + (k3 << 4) + ((hi & 7) << 8)] = z;
        }
    }
    bar_lds();
    // All threads read u[n2], n2 = 0..7: reader (n1=lo, k3=hi) -> addr = t + 256*n2
    float2 u[16];
    #pragma unroll
    for (int n2 = 0; n2 < 8; ++n2)
        u[n2] = sd[t + (n2 << 8)];
    bar_lds();
    // ---- RT1, chunk 1 (n2 >= 8): high waves write ----
    if (!lowhalf) {
        #pragma unroll
        for (int k3 = 0; k3 < 16; ++k3) {
            float2 z = v[POS(k3)];
            if (k3 & 3)  z = cmul(z, b[k3 & 3]);
            if (k3 >> 2) z = cmul(z, c[k3 >> 2]);
            sd[lo + (k3 << 4) + ((hi & 7) << 8)] = z;
        }
    }
    bar_lds();
    #pragma unroll
    for (int n2 = 8; n2 < 16; ++n2)
        u[n2] = sd[t + ((n2 & 7) << 8)];
    bar_lds();   // sd about to be overwritten by RT2 chunk 0

    // ---- Stage B: DFT16 over n2 ----
    dft16(u);

    // Twiddle W4096^{n1*(k3+16*k2)} = Pw[k2&3]*zz[k2>>2]  (n1 = lo, k3 = hi)
    float2 Pw[4], zz[4];
    {
        float sn, cs;
        __sincosf((float)(lo * hi) * NEG2PI_4096, &sn, &cs);
        const float2 P = make_float2(cs, sn);
        __sincosf((float)lo * NEG2PI_256, &sn, &cs);
        float2 w1 = make_float2(cs, sn);          // W4096^{16*n1}
        float2 w2 = cmul(w1, w1);
        float2 w3 = cmul(w2, w1);
        Pw[0] = P;
        Pw[1] = cmul(P, w1);
        Pw[2] = cmul(P, w2);
        Pw[3] = cmul(P, w3);
        zz[0] = make_float2(1.f, 0.f);
        zz[1] = cmul(w2, w2);                     // W256^{4*n1}
        zz[2] = cmul(zz[1], zz[1]);
        zz[3] = cmul(zz[2], zz[1]);
    }
    const int wb2 = (lo ^ hi) + (hi << 4);        // (n1^k3) + 16*k3

    // ---- RT2, chunk 0: all waves write k2 = 0..7 ----
    #pragma unroll
    for (int k2 = 0; k2 < 8; ++k2) {
        float2 z = cmul(u[POS(k2)], Pw[k2 & 3]);
        if (k2 >> 2) z = cmul(z, zz[k2 >> 2]);
        sd[wb2 + (k2 << 8)] = z;
    }
    bar_lds();
    // Low waves (k2 = hi < 8) read w[n1]: addr = (m^lo) + 16*lo + 256*hi
    float2 w[16];
    if (lowhalf) {
        #pragma unroll
        for (int m = 0; m < 16; ++m)
            w[m] = sd[(m ^ lo) + (lo << 4) + ((hi & 7) << 8)];
    }
    bar_lds();
    // ---- RT2, chunk 1: all waves write k2 = 8..15 ----
    #pragma unroll
    for (int k2 = 8; k2 < 16; ++k2) {
        float2 z = cmul(u[POS(k2)], Pw[k2 & 3]);
        z = cmul(z, zz[k2 >> 2]);
        sd[wb2 + ((k2 & 7) << 8)] = z;
    }
    bar_lds();
    if (!lowhalf) {
        #pragma unroll
        for (int m = 0; m < 16; ++m)
            w[m] = sd[(m ^ lo) + (lo << 4) + ((hi & 7) << 8)];
    }

    // ---- Stage C: DFT16 over n1; coalesced nontemporal stride-256 scatter ----
    dft16(w);
    float* yr = yre + off;
    float* yi = yim + off;
    #pragma unroll
    for (int k1 = 0; k1 < 16; ++k1) {
        __builtin_nontemporal_store(w[POS(k1)].x, &yr[t + (k1 << 8)]);
        __builtin_nontemporal_store(w[POS(k1)].y, &yi[t + (k1 << 8)]);
    }
}

extern "C" void kernel_launch(void* const* d_in, const int* in_sizes, int n_in,
                              void* d_out, int out_size, void* d_ws, size_t ws_size,
                              hipStream_t stream) {
    const float* xre = (const float*)d_in[0];
    const float* xim = (const float*)d_in[1];
    const int total = in_sizes[0];          // B * N
    const int rows  = total / FFT_N;        // 2048
    float* yre = (float*)d_out;
    float* yim = yre + total;
    fft4096_r16c<<<dim3(rows), dim3(THREADS), 0, stream>>>(xre, xim, yre, yim);
}

// Round 11
// 26.847 us; speedup vs baseline: 1.0136x; 1.0136x over previous
//
#include <hip/hip_runtime.h>
#include <math.h>

#define FFT_N   4096
#define THREADS 256
#define RPB     4                    // rows per block (pipelined)
#define RH 0.70710678118654752f
#define C16 0.92387953251128676f     // cos(2*pi/16)
#define S16 0.38268343236508977f     // sin(2*pi/16)
#define NEG2PI_256  (-2.45436926061702597e-2f)   // -2*pi/256
#define NEG2PI_4096 (-1.53398078788564123e-3f)   // -2*pi/4096

// Output-position map of dft16: X[k] lives in v[POS(k)].
#define POS(k) ((((k) & 3) << 2) | ((k) >> 2))

__device__ __forceinline__ float2 cmul(float2 a, float2 b) {
    return make_float2(a.x * b.x - a.y * b.y, a.x * b.y + a.y * b.x);
}

// Barrier without vmcnt drain, with full compiler-fence semantics:
// wait+barrier fused in ONE asm (memory clobber fences both sides; nothing
// can be scheduled between the lgkmcnt wait and the s_barrier).
__device__ __forceinline__ void bar_lds() {
    asm volatile("s_waitcnt lgkmcnt(0)\n\ts_barrier" ::: "memory");
}

// In-place DFT-4 (W4 = -i): natural in, natural out.
__device__ __forceinline__ void dft4(float2& a, float2& b, float2& c, float2& d) {
    float2 t0 = make_float2(a.x + c.x, a.y + c.y);
    float2 t1 = make_float2(a.x - c.x, a.y - c.y);
    float2 t2 = make_float2(b.x + d.x, b.y + d.y);
    float2 t3 = make_float2(b.y - d.y, d.x - b.x);   // -i * (b - d)
    a = make_float2(t0.x + t2.x, t0.y + t2.y);
    b = make_float2(t1.x + t3.x, t1.y + t3.y);
    c = make_float2(t0.x - t2.x, t0.y - t2.y);
    d = make_float2(t1.x - t3.x, t1.y - t3.y);
}

// Multiply by W16^E = exp(-2*pi*i*E/16); constant-folded forms.
template<int E>
__device__ __forceinline__ float2 mw16(float2 z) {
    if constexpr (E == 0) return z;
    else if constexpr (E == 4) return make_float2(z.y, -z.x);                    // -i
    else if constexpr (E == 2) return make_float2(RH * (z.x + z.y), RH * (z.y - z.x));
    else if constexpr (E == 6) return make_float2(RH * (z.y - z.x), -RH * (z.x + z.y));
    else if constexpr (E == 1) return cmul(z, make_float2(C16, -S16));
    else if constexpr (E == 3) return cmul(z, make_float2(S16, -C16));
    else /* E == 9 */          return cmul(z, make_float2(-C16, S16));
}

// 16-point DFT, natural input order; output X[k] at v[POS(k)].
__device__ __forceinline__ void dft16(float2 (&v)[16]) {
    dft4(v[0], v[4], v[8],  v[12]);
    dft4(v[1], v[5], v[9],  v[13]);
    dft4(v[2], v[6], v[10], v[14]);
    dft4(v[3], v[7], v[11], v[15]);
    v[5]  = mw16<1>(v[5]);   v[9]  = mw16<2>(v[9]);   v[13] = mw16<3>(v[13]);
    v[6]  = mw16<2>(v[6]);   v[10] = mw16<4>(v[10]);  v[14] = mw16<6>(v[14]);
    v[7]  = mw16<3>(v[7]);   v[11] = mw16<6>(v[11]);  v[15] = mw16<9>(v[15]);
    dft4(v[0],  v[1],  v[2],  v[3]);
    dft4(v[4],  v[5],  v[6],  v[7]);
    dft4(v[8],  v[9],  v[10], v[11]);
    dft4(v[12], v[13], v[14], v[15]);
}

// One full 4096-point row (verified round-5/7 skeleton).
// 4096 = 16*16*16 DIT: n = n1 + 16*n2 + 256*n3, k = k3 + 16*k2 + 256*k1.
// If PF: issue next row's 32 global loads between RT2-write and its barrier —
// they complete under RT2-read + stage C + stores + next row's stage A.
template<bool PF>
__device__ __forceinline__ void process_row(
    float2 (&v)[16], float2 (&vn)[16], float2* __restrict__ sd,
    const int t, const int lo, const int hi,
    const float2 (&b)[4], const float2 (&c)[4],
    const float2 (&Pw)[4], const float2 (&zz)[4], const int wb2,
    const float* __restrict__ xr_n, const float* __restrict__ xi_n,
    float* __restrict__ yr, float* __restrict__ yi)
{
    // ---- Stage A: DFT16 over n3 (thread t = n1 + 16*n2) ----
    dft16(v);

    // Twiddle W256^{n2*k3} = b[k3&3]*c[k3>>2]; write RT1: sd[t + 256*k3]
    #pragma unroll
    for (int k3 = 0; k3 < 16; ++k3) {
        float2 z = v[POS(k3)];
        if (k3 & 3)  z = cmul(z, b[k3 & 3]);
        if (k3 >> 2) z = cmul(z, c[k3 >> 2]);
        sd[t + (k3 << 8)] = z;
    }
    bar_lds();

    // RT1 read: u[n2] = sd[n1 + 16*n2 + 256*k3]
    #pragma unroll
    for (int n2 = 0; n2 < 16; ++n2)
        v[n2] = sd[lo + (n2 << 4) + (hi << 8)];
    bar_lds();   // sd reused by RT2 writes

    // ---- Stage B: DFT16 over n2 ----
    dft16(v);

    // Twiddle W4096^{n1*(k3+16*k2)} = Pw[k2&3]*zz[k2>>2]; write RT2 swizzled:
    // sd[(k3^n1) + 16*k2 + 256*n1]   (wb2 = (hi^lo) + 256*lo, R7-verified)
    #pragma unroll
    for (int k2 = 0; k2 < 16; ++k2) {
        float2 u = cmul(v[POS(k2)], Pw[k2 & 3]);
        if (k2 >> 2) u = cmul(u, zz[k2 >> 2]);
        sd[wb2 + (k2 << 4)] = u;
    }

    // ---- Prefetch next row (issue only; no wait here) ----
    if constexpr (PF) {
        #pragma unroll
        for (int n3 = 0; n3 < 16; ++n3) {
            vn[n3].x = xr_n[t + (n3 << 8)];
            vn[n3].y = xi_n[t + (n3 << 8)];
        }
    }
    bar_lds();

    // RT2 read: w[n1] = sd[(k3^n1) + 16*k2 + 256*n1]
    #pragma unroll
    for (int m = 0; m < 16; ++m)
        v[m] = sd[(lo ^ m) + (hi << 4) + (m << 8)];

    // ---- Stage C: DFT16 over n1; coalesced nontemporal stride-256 scatter ----
    dft16(v);
    #pragma unroll
    for (int k1 = 0; k1 < 16; ++k1) {
        __builtin_nontemporal_store(v[POS(k1)].x, &yr[t + (k1 << 8)]);
        __builtin_nontemporal_store(v[POS(k1)].y, &yi[t + (k1 << 8)]);
    }
    bar_lds();   // all RT2 reads done -> sd free for next row's RT1 writes
}

__global__ __launch_bounds__(THREADS)
void fft4096_pipe(const float* __restrict__ xre, const float* __restrict__ xim,
                  float* __restrict__ yre, float* __restrict__ yim)
{
    __shared__ float2 sd[FFT_N];   // 32 KB

    const int t  = threadIdx.x;
    const int lo = t & 15;
    const int hi = t >> 4;

    // Hoisted row-invariant twiddle constants.
    float2 b[4], c[4], Pw[4], zz[4];
    {
        float sn, cs;
        __sincosf((float)hi * NEG2PI_256, &sn, &cs);
        b[0] = make_float2(1.f, 0.f);
        b[1] = make_float2(cs, sn);
        b[2] = cmul(b[1], b[1]);
        b[3] = cmul(b[2], b[1]);
        c[0] = make_float2(1.f, 0.f);
        c[1] = cmul(b[2], b[2]);        // W256^{4*hi}
        c[2] = cmul(c[1], c[1]);
        c[3] = cmul(c[2], c[1]);
        __sincosf((float)(lo * hi) * NEG2PI_4096, &sn, &cs);
        const float2 P = make_float2(cs, sn);
        __sincosf((float)lo * NEG2PI_256, &sn, &cs);
        float2 w1 = make_float2(cs, sn);          // W4096^{16*n1}
        float2 w2 = cmul(w1, w1);
        float2 w3 = cmul(w2, w1);
        Pw[0] = P;
        Pw[1] = cmul(P, w1);
        Pw[2] = cmul(P, w2);
        Pw[3] = cmul(P, w3);
        zz[0] = make_float2(1.f, 0.f);
        zz[1] = cmul(w2, w2);                     // W256^{4*n1}
        zz[2] = cmul(zz[1], zz[1]);
        zz[3] = cmul(zz[2], zz[1]);
    }
    const int wb2 = (lo ^ hi) + (lo << 8);   // FIXED: was (hi<<4) in R9/R10 (layout bug)

    // 4 consecutive rows per block, ping-pong pipelined.
    const size_t r0 = (size_t)blockIdx.x * RPB * FFT_N;
    const float* xr = xre + r0;
    const float* xi = xim + r0;
    float*       yr = yre + r0;
    float*       yi = yim + r0;

    float2 va[16], vb[16];
    #pragma unroll
    for (int n3 = 0; n3 < 16; ++n3) {            // load row 0
        va[n3].x = xr[t + (n3 << 8)];
        va[n3].y = xi[t + (n3 << 8)];
    }

    process_row<true >(va, vb, sd, t, lo, hi, b, c, Pw, zz, wb2,
                       xr + FFT_N,     xi + FFT_N,     yr,             yi);
    process_row<true >(vb, va, sd, t, lo, hi, b, c, Pw, zz, wb2,
                       xr + 2 * FFT_N, xi + 2 * FFT_N, yr + FFT_N,     yi + FFT_N);
    process_row<true >(va, vb, sd, t, lo, hi, b, c, Pw, zz, wb2,
                       xr + 3 * FFT_N, xi + 3 * FFT_N, yr + 2 * FFT_N, yi + 2 * FFT_N);
    process_row<false>(vb, va, sd, t, lo, hi, b, c, Pw, zz, wb2,
                       xr,             xi,             yr + 3 * FFT_N, yi + 3 * FFT_N);
}

extern "C" void kernel_launch(void* const* d_in, const int* in_sizes, int n_in,
                              void* d_out, int out_size, void* d_ws, size_t ws_size,
                              hipStream_t stream) {
    const float* xre = (const float*)d_in[0];
    const float* xim = (const float*)d_in[1];
    const int total = in_sizes[0];          // B * N
    const int rows  = total / FFT_N;        // 2048
    float* yre = (float*)d_out;
    float* yim = yre + total;
    fft4096_pipe<<<dim3(rows / RPB), dim3(THREADS), 0, stream>>>(xre, xim, yre, yim);
}

// Round 12
// 26.454 us; speedup vs baseline: 1.0286x; 1.0148x over previous
//
#include <hip/hip_runtime.h>
#include <math.h>

#define FFT_N   4096
#define THREADS 256
#define RPB     4                    // rows per block (pipelined)
#define RH 0.70710678118654752f
#define C16 0.92387953251128676f     // cos(2*pi/16)
#define S16 0.38268343236508977f     // sin(2*pi/16)
#define NEG2PI_256  (-2.45436926061702597e-2f)   // -2*pi/256
#define NEG2PI_4096 (-1.53398078788564123e-3f)   // -2*pi/4096

// Output-position map of dft16: X[k] lives in v[POS(k)].
#define POS(k) ((((k) & 3) << 2) | ((k) >> 2))

__device__ __forceinline__ float2 cmul(float2 a, float2 b) {
    return make_float2(a.x * b.x - a.y * b.y, a.x * b.y + a.y * b.x);
}

// Barrier without vmcnt drain, with full compiler-fence semantics:
// wait+barrier fused in ONE asm (memory clobber fences both sides; nothing
// can be scheduled between the lgkmcnt wait and the s_barrier).
__device__ __forceinline__ void bar_lds() {
    asm volatile("s_waitcnt lgkmcnt(0)\n\ts_barrier" ::: "memory");
}

// In-place DFT-4 (W4 = -i): natural in, natural out.
__device__ __forceinline__ void dft4(float2& a, float2& b, float2& c, float2& d) {
    float2 t0 = make_float2(a.x + c.x, a.y + c.y);
    float2 t1 = make_float2(a.x - c.x, a.y - c.y);
    float2 t2 = make_float2(b.x + d.x, b.y + d.y);
    float2 t3 = make_float2(b.y - d.y, d.x - b.x);   // -i * (b - d)
    a = make_float2(t0.x + t2.x, t0.y + t2.y);
    b = make_float2(t1.x + t3.x, t1.y + t3.y);
    c = make_float2(t0.x - t2.x, t0.y - t2.y);
    d = make_float2(t1.x - t3.x, t1.y - t3.y);
}

// Multiply by W16^E = exp(-2*pi*i*E/16); constant-folded forms.
template<int E>
__device__ __forceinline__ float2 mw16(float2 z) {
    if constexpr (E == 0) return z;
    else if constexpr (E == 4) return make_float2(z.y, -z.x);                    // -i
    else if constexpr (E == 2) return make_float2(RH * (z.x + z.y), RH * (z.y - z.x));
    else if constexpr (E == 6) return make_float2(RH * (z.y - z.x), -RH * (z.x + z.y));
    else if constexpr (E == 1) return cmul(z, make_float2(C16, -S16));
    else if constexpr (E == 3) return cmul(z, make_float2(S16, -C16));
    else /* E == 9 */          return cmul(z, make_float2(-C16, S16));
}

// 16-point DFT, natural input order; output X[k] at v[POS(k)].
__device__ __forceinline__ void dft16(float2 (&v)[16]) {
    dft4(v[0], v[4], v[8],  v[12]);
    dft4(v[1], v[5], v[9],  v[13]);
    dft4(v[2], v[6], v[10], v[14]);
    dft4(v[3], v[7], v[11], v[15]);
    v[5]  = mw16<1>(v[5]);   v[9]  = mw16<2>(v[9]);   v[13] = mw16<3>(v[13]);
    v[6]  = mw16<2>(v[6]);   v[10] = mw16<4>(v[10]);  v[14] = mw16<6>(v[14]);
    v[7]  = mw16<3>(v[7]);   v[11] = mw16<6>(v[11]);  v[15] = mw16<9>(v[15]);
    dft4(v[0],  v[1],  v[2],  v[3]);
    dft4(v[4],  v[5],  v[6],  v[7]);
    dft4(v[8],  v[9],  v[10], v[11]);
    dft4(v[12], v[13], v[14], v[15]);
}

// One full 4096-point row (verified round-5/7/11 skeleton).
// 4096 = 16*16*16 DIT: n = n1 + 16*n2 + 256*n3, k = k3 + 16*k2 + 256*k1.
// If PF: issue next row's 32 global loads at the TOP — they drain under this
// row's entire compute+DS and are consumed at next row's stage A.
template<bool PF>
__device__ __forceinline__ void process_row(
    float2 (&v)[16], float2 (&vn)[16], float2* __restrict__ sd,
    const int t, const int lo, const int hi,
    const float2 (&b)[4], const float2 (&c)[4],
    const float2 (&Pw)[4], const float2 (&zz)[4], const int wb2,
    const float* __restrict__ xr_n, const float* __restrict__ xi_n,
    float* __restrict__ yr, float* __restrict__ yi)
{
    // ---- Prefetch next row FIRST (issue only; consumed next call) ----
    if constexpr (PF) {
        #pragma unroll
        for (int n3 = 0; n3 < 16; ++n3) {
            vn[n3].x = xr_n[t + (n3 << 8)];
            vn[n3].y = xi_n[t + (n3 << 8)];
        }
    }

    // ---- Stage A: DFT16 over n3 (thread t = n1 + 16*n2) ----
    dft16(v);

    // Twiddle W256^{n2*k3} = b[k3&3]*c[k3>>2]; write RT1: sd[t + 256*k3]
    #pragma unroll
    for (int k3 = 0; k3 < 16; ++k3) {
        float2 z = v[POS(k3)];
        if (k3 & 3)  z = cmul(z, b[k3 & 3]);
        if (k3 >> 2) z = cmul(z, c[k3 >> 2]);
        sd[t + (k3 << 8)] = z;
    }
    bar_lds();

    // RT1 read: u[n2] = sd[n1 + 16*n2 + 256*k3]
    #pragma unroll
    for (int n2 = 0; n2 < 16; ++n2)
        v[n2] = sd[lo + (n2 << 4) + (hi << 8)];
    bar_lds();   // sd reused by RT2 writes

    // ---- Stage B: DFT16 over n2 ----
    dft16(v);

    // Twiddle W4096^{n1*(k3+16*k2)} = Pw[k2&3]*zz[k2>>2]; write RT2 swizzled:
    // sd[(k3^n1) + 16*k2 + 256*n1]   (wb2 = (hi^lo) + 256*lo, R7-verified)
    #pragma unroll
    for (int k2 = 0; k2 < 16; ++k2) {
        float2 u = cmul(v[POS(k2)], Pw[k2 & 3]);
        if (k2 >> 2) u = cmul(u, zz[k2 >> 2]);
        sd[wb2 + (k2 << 4)] = u;
    }
    bar_lds();

    // RT2 read: w[n1] = sd[(k3^n1) + 16*k2 + 256*n1]
    #pragma unroll
    for (int m = 0; m < 16; ++m)
        v[m] = sd[(lo ^ m) + (hi << 4) + (m << 8)];

    // ---- Stage C: DFT16 over n1; coalesced nontemporal stride-256 scatter ----
    dft16(v);
    #pragma unroll
    for (int k1 = 0; k1 < 16; ++k1) {
        __builtin_nontemporal_store(v[POS(k1)].x, &yr[t + (k1 << 8)]);
        __builtin_nontemporal_store(v[POS(k1)].y, &yi[t + (k1 << 8)]);
    }
    bar_lds();   // all RT2 reads done -> sd free for next row's RT1 writes
}

__global__ __launch_bounds__(THREADS)
void fft4096_pipe(const float* __restrict__ xre, const float* __restrict__ xim,
                  float* __restrict__ yre, float* __restrict__ yim)
{
    __shared__ float2 sd[FFT_N];   // 32 KB

    const int t  = threadIdx.x;
    const int lo = t & 15;
    const int hi = t >> 4;

    // Hoisted row-invariant twiddle constants.
    float2 b[4], c[4], Pw[4], zz[4];
    {
        float sn, cs;
        __sincosf((float)hi * NEG2PI_256, &sn, &cs);
        b[0] = make_float2(1.f, 0.f);
        b[1] = make_float2(cs, sn);
        b[2] = cmul(b[1], b[1]);
        b[3] = cmul(b[2], b[1]);
        c[0] = make_float2(1.f, 0.f);
        c[1] = cmul(b[2], b[2]);        // W256^{4*hi}
        c[2] = cmul(c[1], c[1]);
        c[3] = cmul(c[2], c[1]);
        __sincosf((float)(lo * hi) * NEG2PI_4096, &sn, &cs);
        const float2 P = make_float2(cs, sn);
        __sincosf((float)lo * NEG2PI_256, &sn, &cs);
        float2 w1 = make_float2(cs, sn);          // W4096^{16*n1}
        float2 w2 = cmul(w1, w1);
        float2 w3 = cmul(w2, w1);
        Pw[0] = P;
        Pw[1] = cmul(P, w1);
        Pw[2] = cmul(P, w2);
        Pw[3] = cmul(P, w3);
        zz[0] = make_float2(1.f, 0.f);
        zz[1] = cmul(w2, w2);                     // W256^{4*n1}
        zz[2] = cmul(zz[1], zz[1]);
        zz[3] = cmul(zz[2], zz[1]);
    }
    const int wb2 = (lo ^ hi) + (lo << 8);

    // 4 consecutive rows per block, ping-pong pipelined.
    const size_t r0 = (size_t)blockIdx.x * RPB * FFT_N;
    const float* xr = xre + r0;
    const float* xi = xim + r0;
    float*       yr = yre + r0;
    float*       yi = yim + r0;

    float2 va[16], vb[16];
    #pragma unroll
    for (int n3 = 0; n3 < 16; ++n3) {            // load row 0
        va[n3].x = xr[t + (n3 << 8)];
        va[n3].y = xi[t + (n3 << 8)];
    }

    process_row<true >(va, vb, sd, t, lo, hi, b, c, Pw, zz, wb2,
                       xr + FFT_N,     xi + FFT_N,     yr,             yi);
    process_row<true >(vb, va, sd, t, lo, hi, b, c, Pw, zz, wb2,
                       xr + 2 * FFT_N, xi + 2 * FFT_N, yr + FFT_N,     yi + FFT_N);
    process_row<true >(va, vb, sd, t, lo, hi, b, c, Pw, zz, wb2,
                       xr + 3 * FFT_N, xi + 3 * FFT_N, yr + 2 * FFT_N, yi + 2 * FFT_N);
    process_row<false>(vb, va, sd, t, lo, hi, b, c, Pw, zz, wb2,
                       xr,             xi,             yr + 3 * FFT_N, yi + 3 * FFT_N);
}

extern "C" void kernel_launch(void* const* d_in, const int* in_sizes, int n_in,
                              void* d_out, int out_size, void* d_ws, size_t ws_size,
                              hipStream_t stream) {
    const float* xre = (const float*)d_in[0];
    const float* xim = (const float*)d_in[1];
    const int total = in_sizes[0];          // B * N
    const int rows  = total / FFT_N;        // 2048
    float* yre = (float*)d_out;
    float* yim = yre + total;
    fft4096_pipe<<<dim3(rows / RPB), dim3(THREADS), 0, stream>>>(xre, xim, yre, yim);
}

// Round 13
// 26.092 us; speedup vs baseline: 1.0429x; 1.0139x over previous
//
#include <hip/hip_runtime.h>
#include <math.h>

#define FFT_N   4096
#define THREADS 256
#define RPB     4                    // rows per block (pipelined)
#define RH 0.70710678118654752f
#define C16 0.92387953251128676f     // cos(2*pi/16)
#define S16 0.38268343236508977f     // sin(2*pi/16)
#define NEG2PI_256  (-2.45436926061702597e-2f)   // -2*pi/256
#define NEG2PI_4096 (-1.53398078788564123e-3f)   // -2*pi/4096

// Output-position map of dft16: X[k] lives in v[POS(k)].
#define POS(k) ((((k) & 3) << 2) | ((k) >> 2))

__device__ __forceinline__ float2 cmul(float2 a, float2 b) {
    return make_float2(a.x * b.x - a.y * b.y, a.x * b.y + a.y * b.x);
}

// Barrier without vmcnt drain, with full compiler-fence semantics:
// wait+barrier fused in ONE asm. Prefetch loads / deferred stores stay
// in flight across it (vmcnt untouched).
__device__ __forceinline__ void bar_lds() {
    asm volatile("s_waitcnt lgkmcnt(0)\n\ts_barrier" ::: "memory");
}

// In-place DFT-4 (W4 = -i): natural in, natural out.
__device__ __forceinline__ void dft4(float2& a, float2& b, float2& c, float2& d) {
    float2 t0 = make_float2(a.x + c.x, a.y + c.y);
    float2 t1 = make_float2(a.x - c.x, a.y - c.y);
    float2 t2 = make_float2(b.x + d.x, b.y + d.y);
    float2 t3 = make_float2(b.y - d.y, d.x - b.x);   // -i * (b - d)
    a = make_float2(t0.x + t2.x, t0.y + t2.y);
    b = make_float2(t1.x + t3.x, t1.y + t3.y);
    c = make_float2(t0.x - t2.x, t0.y - t2.y);
    d = make_float2(t1.x - t3.x, t1.y - t3.y);
}

// Multiply by W16^E = exp(-2*pi*i*E/16); constant-folded forms.
template<int E>
__device__ __forceinline__ float2 mw16(float2 z) {
    if constexpr (E == 0) return z;
    else if constexpr (E == 4) return make_float2(z.y, -z.x);                    // -i
    else if constexpr (E == 2) return make_float2(RH * (z.x + z.y), RH * (z.y - z.x));
    else if constexpr (E == 6) return make_float2(RH * (z.y - z.x), -RH * (z.x + z.y));
    else if constexpr (E == 1) return cmul(z, make_float2(C16, -S16));
    else if constexpr (E == 3) return cmul(z, make_float2(S16, -C16));
    else /* E == 9 */          return cmul(z, make_float2(-C16, S16));
}

// 16-point DFT, natural input order; output X[k] at v[POS(k)].
__device__ __forceinline__ void dft16(float2 (&v)[16]) {
    dft4(v[0], v[4], v[8],  v[12]);
    dft4(v[1], v[5], v[9],  v[13]);
    dft4(v[2], v[6], v[10], v[14]);
    dft4(v[3], v[7], v[11], v[15]);
    v[5]  = mw16<1>(v[5]);   v[9]  = mw16<2>(v[9]);   v[13] = mw16<3>(v[13]);
    v[6]  = mw16<2>(v[6]);   v[10] = mw16<4>(v[10]);  v[14] = mw16<6>(v[14]);
    v[7]  = mw16<3>(v[7]);   v[11] = mw16<6>(v[11]);  v[15] = mw16<9>(v[15]);
    dft4(v[0],  v[1],  v[2],  v[3]);
    dft4(v[4],  v[5],  v[6],  v[7]);
    dft4(v[8],  v[9],  v[10], v[11]);
    dft4(v[12], v[13], v[14], v[15]);
}

// One full 4096-point row (verified R5/R7/R12 skeleton), with fine-grained
// VMEM streaming: next row's loads (PF) and previous row's stores (ST) are
// split into 4 quad-packs each and interleaved into every phase gap, so the
// memory system sees a continuous read+write mix instead of macro-bursts.
// 4096 = 16*16*16 DIT: n = n1 + 16*n2 + 256*n3, k = k3 + 16*k2 + 256*k1.
template<bool PF, bool ST>
__device__ __forceinline__ void process_row(
    float2 (&v)[16], float2 (&vn)[16], float2 (&vo)[16],
    float2* __restrict__ sd,
    const int t, const int lo, const int hi,
    const float2 (&b)[4], const float2 (&c)[4],
    const float2 (&Pw)[4], const float2 (&zz)[4], const int wb2,
    const float* __restrict__ xr_n, const float* __restrict__ xi_n,
    float* __restrict__ yr_p, float* __restrict__ yi_p)
{
    // Quad-pack helpers (8 VMEM instrs each).
#define LPACK(q)                                                         \
    if constexpr (PF) {                                                  \
        _Pragma("unroll")                                                \
        for (int n3 = 4*(q); n3 < 4*(q)+4; ++n3) {                       \
            vn[n3].x = xr_n[t + (n3 << 8)];                              \
            vn[n3].y = xi_n[t + (n3 << 8)];                              \
        }                                                                \
    }
#define SPACK(q)                                                         \
    if constexpr (ST) {                                                  \
        _Pragma("unroll")                                                \
        for (int k1 = 4*(q); k1 < 4*(q)+4; ++k1) {                       \
            __builtin_nontemporal_store(vo[k1].x, &yr_p[t + (k1 << 8)]); \
            __builtin_nontemporal_store(vo[k1].y, &yi_p[t + (k1 << 8)]); \
        }                                                                \
    }

    LPACK(0)

    // ---- Stage A: DFT16 over n3 (thread t = n1 + 16*n2) ----
    dft16(v);
    SPACK(0)

    // Twiddle W256^{n2*k3} = b[k3&3]*c[k3>>2]; write RT1: sd[t + 256*k3]
    #pragma unroll
    for (int k3 = 0; k3 < 16; ++k3) {
        float2 z = v[POS(k3)];
        if (k3 & 3)  z = cmul(z, b[k3 & 3]);
        if (k3 >> 2) z = cmul(z, c[k3 >> 2]);
        sd[t + (k3 << 8)] = z;
    }
    LPACK(1)
    bar_lds();

    // RT1 read: u[n2] = sd[n1 + 16*n2 + 256*k3]
    #pragma unroll
    for (int n2 = 0; n2 < 16; ++n2)
        v[n2] = sd[lo + (n2 << 4) + (hi << 8)];
    SPACK(1)
    bar_lds();   // sd reused by RT2 writes

    // ---- Stage B: DFT16 over n2 ----
    dft16(v);
    LPACK(2)
    SPACK(2)

    // Twiddle W4096^{n1*(k3+16*k2)} = Pw[k2&3]*zz[k2>>2]; write RT2 swizzled:
    // sd[(k3^n1) + 16*k2 + 256*n1]   (wb2 = (hi^lo) + 256*lo, R7-verified)
    #pragma unroll
    for (int k2 = 0; k2 < 16; ++k2) {
        float2 u = cmul(v[POS(k2)], Pw[k2 & 3]);
        if (k2 >> 2) u = cmul(u, zz[k2 >> 2]);
        sd[wb2 + (k2 << 4)] = u;
    }
    SPACK(3)    // last store pack BEFORE vo is overwritten below
    bar_lds();

    // RT2 read: w[n1] = sd[(k3^n1) + 16*k2 + 256*n1]
    #pragma unroll
    for (int m = 0; m < 16; ++m)
        v[m] = sd[(lo ^ m) + (hi << 4) + (m << 8)];
    LPACK(3)

    // ---- Stage C: DFT16 over n1; outputs DEFERRED into vo (stored next row) ----
    dft16(v);
    #pragma unroll
    for (int k1 = 0; k1 < 16; ++k1)
        vo[k1] = v[POS(k1)];
    bar_lds();   // all RT2 reads done -> sd free for next row's RT1 writes

#undef LPACK
#undef SPACK
}

__global__ __launch_bounds__(THREADS)
void fft4096_stream(const float* __restrict__ xre, const float* __restrict__ xim,
                    float* __restrict__ yre, float* __restrict__ yim)
{
    __shared__ float2 sd[FFT_N];   // 32 KB

    const int t  = threadIdx.x;
    const int lo = t & 15;
    const int hi = t >> 4;

    // Hoisted row-invariant twiddle constants.
    float2 b[4], c[4], Pw[4], zz[4];
    {
        float sn, cs;
        __sincosf((float)hi * NEG2PI_256, &sn, &cs);
        b[0] = make_float2(1.f, 0.f);
        b[1] = make_float2(cs, sn);
        b[2] = cmul(b[1], b[1]);
        b[3] = cmul(b[2], b[1]);
        c[0] = make_float2(1.f, 0.f);
        c[1] = cmul(b[2], b[2]);        // W256^{4*hi}
        c[2] = cmul(c[1], c[1]);
        c[3] = cmul(c[2], c[1]);
        __sincosf((float)(lo * hi) * NEG2PI_4096, &sn, &cs);
        const float2 P = make_float2(cs, sn);
        __sincosf((float)lo * NEG2PI_256, &sn, &cs);
        float2 w1 = make_float2(cs, sn);          // W4096^{16*n1}
        float2 w2 = cmul(w1, w1);
        float2 w3 = cmul(w2, w1);
        Pw[0] = P;
        Pw[1] = cmul(P, w1);
        Pw[2] = cmul(P, w2);
        Pw[3] = cmul(P, w3);
        zz[0] = make_float2(1.f, 0.f);
        zz[1] = cmul(w2, w2);                     // W256^{4*n1}
        zz[2] = cmul(zz[1], zz[1]);
        zz[3] = cmul(zz[2], zz[1]);
    }
    const int wb2 = (lo ^ hi) + (lo << 8);

    // 4 consecutive rows per block: loads 1 row ahead, stores 1 row behind.
    const size_t r0 = (size_t)blockIdx.x * RPB * FFT_N;
    const float* xr = xre + r0;
    const float* xi = xim + r0;
    float*       yr = yre + r0;
    float*       yi = yim + r0;

    float2 va[16], vb[16], vo[16];
    #pragma unroll
    for (int n3 = 0; n3 < 16; ++n3) {            // load row 0 (prologue burst)
        va[n3].x = xr[t + (n3 << 8)];
        va[n3].y = xi[t + (n3 << 8)];
    }

    // row 0: no deferred stores yet
    process_row<true , false>(va, vb, vo, sd, t, lo, hi, b, c, Pw, zz, wb2,
                              xr + FFT_N,     xi + FFT_N,     yr, yi);
    // row 1: stores row 0
    process_row<true , true >(vb, va, vo, sd, t, lo, hi, b, c, Pw, zz, wb2,
                              xr + 2 * FFT_N, xi + 2 * FFT_N, yr,             yi);
    // row 2: stores row 1
    process_row<true , true >(va, vb, vo, sd, t, lo, hi, b, c, Pw, zz, wb2,
                              xr + 3 * FFT_N, xi + 3 * FFT_N, yr + FFT_N,     yi + FFT_N);
    // row 3: stores row 2, no prefetch
    process_row<false, true >(vb, va, vo, sd, t, lo, hi, b, c, Pw, zz, wb2,
                              xr,             xi,             yr + 2 * FFT_N, yi + 2 * FFT_N);

    // Epilogue: flush row 3's outputs.
    #pragma unroll
    for (int k1 = 0; k1 < 16; ++k1) {
        __builtin_nontemporal_store(vo[k1].x, &yr[3 * FFT_N + t + (k1 << 8)]);
        __builtin_nontemporal_store(vo[k1].y, &yi[3 * FFT_N + t + (k1 << 8)]);
    }
}

extern "C" void kernel_launch(void* const* d_in, const int* in_sizes, int n_in,
                              void* d_out, int out_size, void* d_ws, size_t ws_size,
                              hipStream_t stream) {
    const float* xre = (const float*)d_in[0];
    const float* xim = (const float*)d_in[1];
    const int total = in_sizes[0];          // B * N
    const int rows  = total / FFT_N;        // 2048
    float* yre = (float*)d_out;
    float* yim = yre + total;
    fft4096_stream<<<dim3(rows / RPB), dim3(THREADS), 0, stream>>>(xre, xim, yre, yim);
}